// Round 11
// baseline (238.644 us; speedup 1.0000x reference)
//
#include <hip/hip_runtime.h>
#include <hip/hip_bf16.h>

typedef float f4 __attribute__((ext_vector_type(4)));
typedef int   i4 __attribute__((ext_vector_type(4)));
typedef unsigned short us8 __attribute__((ext_vector_type(8)));
typedef short bfrag __attribute__((ext_vector_type(8)));     // 8 bf16
typedef float f16v __attribute__((ext_vector_type(16)));

constexpr int NN   = 4096;
constexpr int FINc = 512;
constexpr int FOUTc= 128;
constexpr int KHc  = 4;
constexpr int KFc  = 512;
constexpr float LOG2E = 1.44269504088896340736f;

static __device__ __forceinline__ unsigned short f2bf(float f) {
    unsigned u = __float_as_uint(f);
    return (unsigned short)((u + 0x7fffu + ((u >> 16) & 1u)) >> 16);   // RNE
}
static __device__ __forceinline__ float bf2f(unsigned short u) {
    return __uint_as_float(((unsigned)u) << 16);
}
static __device__ __forceinline__ bfrag us2bf(us8 v) {
    union { us8 u; bfrag s; } cv; cv.u = v; return cv.s;
}

// hB fragment layout (bf16): per head k, per 64-m chunk mc:
//   byte = k*1048576 + mc*16384 + ks*4096 + lg*2048 + col*16 + j*2
// where m = ks*16 + lg*8 + j, col in [0,128)

// ---------------- kernel 0: prep: x->xb | W->WbT | zero tickets ----------------
__global__ __launch_bounds__(256) void prep_kernel(const float* __restrict__ x,
                                                   const float* __restrict__ W,
                                                   unsigned short* __restrict__ xb,
                                                   unsigned short* __restrict__ WbT,
                                                   unsigned* __restrict__ ticket) {
    __shared__ float tile[32 * 132];
    const int b = blockIdx.x, t = threadIdx.x;
    if (b < 1024) {                       // x cast: 8 per thread
        size_t base = ((size_t)b * 256 + t) * 8;
        f4 v0 = *(const f4*)&x[base];
        f4 v1 = *(const f4*)&x[base + 4];
        us8 o;
#pragma unroll
        for (int j = 0; j < 4; ++j) { o[j] = f2bf(v0[j]); o[4 + j] = f2bf(v1[j]); }
        *(us8*)&xb[base] = o;
    } else if (b < 1088) {                // W transpose: 64 blocks, 32f x 128o tiles
        const int wb = b - 1024;
        const int k = wb >> 4, f0 = (wb & 15) * 32;
#pragma unroll
        for (int p = 0; p < 4; ++p) {
            int fl = p * 8 + (t >> 5);
            int oc = (t & 31) * 4;
            *(f4*)&tile[fl * 132 + oc] =
                *(const f4*)&W[(size_t)k * 65536 + (size_t)(f0 + fl) * 128 + oc];
        }
        __syncthreads();
        const int o = t >> 1, fh = (t & 1) * 16;
        alignas(16) unsigned short buf[16];
#pragma unroll
        for (int j = 0; j < 16; ++j) buf[j] = f2bf(tile[(fh + j) * 132 + o]);
        unsigned short* dst = &WbT[((size_t)k * 128 + o) * FINc + f0 + fh];
        *(us8*)dst       = *(const us8*)&buf[0];
        *(us8*)(dst + 8) = *(const us8*)&buf[8];
    } else {                              // zero split-K tickets (every launch)
        ticket[t] = 0u;
        ticket[t + 256] = 0u;
    }
}

// ---------------- kernel 1: gemmh (blocks 0..511) | adj->bits (blocks 512..1535) ----------------
__global__ __launch_bounds__(256) void gemmh_bits_kernel(const unsigned short* __restrict__ xb,
                                                         const unsigned short* __restrict__ WbT,
                                                         const int* __restrict__ adj,
                                                         unsigned short* __restrict__ hB,
                                                         unsigned* __restrict__ bits) {
    __shared__ char Ax[64 * 128];
    __shared__ char Bx[64 * 128];
    const int b = blockIdx.x, t = threadIdx.x;
    if (b >= 512) {                       // ---- bits: 1024 blocks x 16384 ints ----
        size_t i0 = (size_t)(b - 512) * 16384 + (size_t)t * 64;
        const int* ap = adj + i0;
        unsigned long long bb = 0ull;
#pragma unroll
        for (int c = 0; c < 16; ++c) {
            i4 v = *(const i4*)(ap + c * 4);
            unsigned n = (v[0] != 0 ? 1u : 0u) | (v[1] != 0 ? 2u : 0u)
                       | (v[2] != 0 ? 4u : 0u) | (v[3] != 0 ? 8u : 0u);
            bb |= (unsigned long long)n << (c * 4);
        }
        *(unsigned long long*)&bits[i0 >> 5] = bb;
        return;
    }
    const int wid = t >> 6, lane = t & 63;
    const int c0 = (b & 7) * 64, n0 = (b >> 3) * 64;
    const int head = c0 >> 7, ob = c0 & 127;
    const int srow = t >> 2, sseg = t & 3;
    const unsigned short* asrc = &xb[(size_t)(n0 + srow) * FINc + sseg * 16];
    const unsigned short* bsrc = &WbT[((size_t)(head * 128 + ob + srow)) * FINc + sseg * 16];
    const int rowbase = (wid & 1) * 32, colbase = (wid >> 1) * 32;
    f16v acc = {};
    for (int fc = 0; fc < FINc; fc += 64) {
        us8 a0 = *(const us8*)(asrc + fc), a1 = *(const us8*)(asrc + fc + 8);
        us8 b0 = *(const us8*)(bsrc + fc), b1 = *(const us8*)(bsrc + fc + 8);
        __syncthreads();
        {
            int byt = (sseg * 32) ^ ((srow & 7) << 4);
            char* pa = Ax + srow * 128;
            *(us8*)(pa + byt) = a0;  *(us8*)(pa + (byt ^ 16)) = a1;
            char* pb = Bx + srow * 128;
            *(us8*)(pb + byt) = b0;  *(us8*)(pb + (byt ^ 16)) = b1;
        }
        __syncthreads();
#pragma unroll
        for (int ks = 0; ks < 4; ++ks) {
            int kb = ks * 32 + ((lane >> 5) << 4);
            int ar = rowbase + (lane & 31);
            bfrag af = *(const bfrag*)(Ax + ar * 128 + (kb ^ ((ar & 7) << 4)));
            int bc = colbase + (lane & 31);
            bfrag bf = *(const bfrag*)(Bx + bc * 128 + (kb ^ ((bc & 7) << 4)));
            acc = __builtin_amdgcn_mfma_f32_32x32x16_bf16(af, bf, acc, 0, 0, 0);
        }
    }
    __syncthreads();
#pragma unroll
    for (int reg = 0; reg < 16; ++reg) {
        int row = rowbase + (reg & 3) + 8 * (reg >> 2) + 4 * (lane >> 5);
        int col = colbase + (lane & 31);
        *(unsigned short*)(Ax + row * 128 + ((col * 2) ^ ((row & 7) << 4))) = f2bf(acc[reg]);
    }
    __syncthreads();
    {
        const int col_l = t & 63;
        unsigned short* dstbase = hB + (size_t)head * 524288 + (size_t)(n0 >> 6) * 8192
                                     + (size_t)(ob + col_l) * 8;
#pragma unroll
        for (int g = 0; g < 2; ++g) {
            int o8 = (t >> 6) + g * 4;
            int ks = o8 >> 1, lg = o8 & 1;
            alignas(16) unsigned short buf[8];
#pragma unroll
            for (int j = 0; j < 8; ++j) {
                int r = o8 * 8 + j;
                buf[j] = *(const unsigned short*)(Ax + r * 128 + ((col_l * 2) ^ ((r & 7) << 4)));
            }
            *(us8*)(dstbase + ks * 2048 + lg * 1024) = *(const us8*)buf;
        }
    }
}

// ---------------- kernel 2: ei[n,k]; EjP/EjN columns (factorized softmax) ----------------
__global__ __launch_bounds__(256) void e2_kernel(const unsigned short* __restrict__ hB,
                                                 const float* __restrict__ a,
                                                 float* __restrict__ ei,
                                                 float* __restrict__ ejP,
                                                 float* __restrict__ ejN) {
    __shared__ unsigned short hs[8192];
    __shared__ float as[128], ad[128];
    __shared__ float pim[4][64], pjm[4][64];
    const int t = threadIdx.x;
    const int k = blockIdx.x >> 6;
    const int mc = blockIdx.x & 63;
    if (t < 128) as[t] = a[k * 256 + t] * LOG2E;
    else         ad[t - 128] = a[k * 256 + t] * LOG2E;
    const unsigned short* src = hB + ((size_t)k * 64 + mc) * 8192;
#pragma unroll
    for (int i = 0; i < 4; ++i) {
        int off = i * 2048 + t * 8;
        *(us8*)&hs[off] = *(const us8*)&src[off];
    }
    __syncthreads();
    const int m = t & 63, wq = t >> 6;
    const int base = (m >> 4) * 2048 + ((m >> 3) & 1) * 1024 + (m & 7);
    float si = 0.f, sj = 0.f;
#pragma unroll
    for (int cc = 0; cc < 32; ++cc) {
        int c = wq * 32 + cc;
        float v = bf2f(hs[base + c * 8]);
        si += v * as[c];
        sj += v * ad[c];
    }
    pim[wq][m] = si; pjm[wq][m] = sj;
    __syncthreads();
    if (t < 64) {
        float siv = pim[0][t] + pim[1][t] + pim[2][t] + pim[3][t];
        float sjv = pjm[0][t] + pjm[1][t] + pjm[2][t] + pjm[3][t];
        ei[(mc * 64 + t) * KHc + k]       = siv;
        ejP[(size_t)k * NN + mc * 64 + t] = exp2f(sjv);
        ejN[(size_t)k * NN + mc * 64 + t] = exp2f(0.2f * sjv);
    }
}

// ---------------- kernel 3: partial out = P' @ H + fused split-K finish ----------------
// P'[n,m] = mask * max(EjP[m], C_n*EjN[m])  (row factor exp2(ei) cancels in softmax).
// 1024 blocks, 4 waves x private 512-m quarter, register-P, no in-loop barriers.
// Second block of each (k,rt) pair (atomic ticket) combines halves and writes out.
__global__ __launch_bounds__(256, 3) void out_mfma_kernel(const unsigned* __restrict__ bits,
                                                          const float* __restrict__ ei,
                                                          const float* __restrict__ ejP,
                                                          const float* __restrict__ ejN,
                                                          const unsigned short* __restrict__ hB,
                                                          float* __restrict__ pacc,
                                                          float* __restrict__ psum,
                                                          unsigned* __restrict__ ticket,
                                                          float* __restrict__ out) {
    __shared__ float arena[4096];          // ejP/ejN planes during loop; red after
    __shared__ unsigned bitsL[4][544];
    __shared__ unsigned mtab[4][4];
    __shared__ float sred[4][32];
    __shared__ unsigned oldt_s;
    float* ejPL = arena;                   // [4][512]
    float* ejNL = arena + 2048;            // [4][512]
    float* red  = arena;                   // 4096 floats, used after loop

    const int bid = blockIdx.x;
    const int nb  = (bid & 7) * 128 + (bid >> 3);   // bijective XCD chunking
    const int k   = nb >> 8;
    const int rt  = (nb & 255) >> 1;
    const int hf  = nb & 1;
    const int n0  = rt * 32;
    const int t = threadIdx.x, lane = t & 63, w = t >> 6;
    const int row = lane & 31, kh = lane >> 5;
    const int mq  = hf * 2048 + w * 512;            // wave's private m range
    if (lane < 4) mtab[w][lane] = ((lane & 1) ? 0xFFFFu : 0u) | ((lane & 2) ? 0xFFFF0000u : 0u);
    {   // stage bits (wave-private)
        int r = lane >> 1, cb = (lane & 1) * 8;
        const unsigned* src = &bits[(size_t)(n0 + r) * 128 + (mq >> 5) + cb];
        unsigned* dst = &bitsL[w][r * 17 + cb];
#pragma unroll
        for (int c = 0; c < 8; ++c) dst[c] = src[c];
    }
    {   // stage EjP/EjN (wave-private)
        const float* sp = &ejP[(size_t)k * NN + mq + lane * 8];
        const float* sn = &ejN[(size_t)k * NN + mq + lane * 8];
        *(f4*)&ejPL[w * 512 + lane * 8]     = *(const f4*)sp;
        *(f4*)&ejPL[w * 512 + lane * 8 + 4] = *(const f4*)(sp + 4);
        *(f4*)&ejNL[w * 512 + lane * 8]     = *(const f4*)sn;
        *(f4*)&ejNL[w * 512 + lane * 8 + 4] = *(const f4*)(sn + 4);
    }
    const float eiv = ei[(n0 + row) * KHc + k];
    const float C = exp2f(-0.8f * eiv);
    const char* hbase = (const char*)hB + (size_t)k * 1048576 + (size_t)(mq >> 6) * 16384
                        + kh * 2048 + row * 16;
    bfrag ones;
#pragma unroll
    for (int j = 0; j < 8; ++j) ones[j] = (short)0x3F80;   // bf16 1.0
    f16v acc0 = {}, acc1 = {}, acc2 = {}, acc3 = {}, accs = {};

    for (int it = 0; it < 8; ++it) {
        const char* hc = hbase + (size_t)it * 16384;
        unsigned bwA = bitsL[w][row * 17 + it * 2];
        unsigned bwB = bitsL[w][row * 17 + it * 2 + 1];
#pragma unroll
        for (int ks = 0; ks < 4; ++ks) {
            us8 hg0 = *(const us8*)(hc + ks * 4096);
            us8 hg1 = *(const us8*)(hc + ks * 4096 + 512);
            us8 hg2 = *(const us8*)(hc + ks * 4096 + 1024);
            us8 hg3 = *(const us8*)(hc + ks * 4096 + 1536);
            const int eb = w * 512 + it * 64 + ks * 16 + kh * 8;
            f4 jp0 = *(const f4*)&ejPL[eb];
            f4 jp1 = *(const f4*)&ejPL[eb + 4];
            f4 jn0 = *(const f4*)&ejNL[eb];
            f4 jn1 = *(const f4*)&ejNL[eb + 4];
            unsigned bw = ((ks & 2) ? bwB : bwA) >> ((ks & 1) * 16 + kh * 8);
            union { unsigned u[4]; bfrag s; } pk;
#pragma unroll
            for (int jj = 0; jj < 4; ++jj) {
                float a0 = (jj < 2) ? jp0[2 * jj]     : jp1[2 * jj - 4];
                float a1 = (jj < 2) ? jp0[2 * jj + 1] : jp1[2 * jj - 3];
                float b0 = (jj < 2) ? jn0[2 * jj]     : jn1[2 * jj - 4];
                float b1 = (jj < 2) ? jn0[2 * jj + 1] : jn1[2 * jj - 3];
                float m0 = fmaxf(a0, C * b0);          // exp2(lrelu) = max of exps
                float m1 = fmaxf(a1, C * b1);
                float2 fp; fp.x = m0; fp.y = m1;
                __hip_bfloat162 b2 = __float22bfloat162_rn(fp);
                pk.u[jj] = (*reinterpret_cast<unsigned*>(&b2)) & mtab[w][(bw >> (2 * jj)) & 3];
            }
            acc0 = __builtin_amdgcn_mfma_f32_32x32x16_bf16(pk.s, us2bf(hg0), acc0, 0, 0, 0);
            acc1 = __builtin_amdgcn_mfma_f32_32x32x16_bf16(pk.s, us2bf(hg1), acc1, 0, 0, 0);
            acc2 = __builtin_amdgcn_mfma_f32_32x32x16_bf16(pk.s, us2bf(hg2), acc2, 0, 0, 0);
            acc3 = __builtin_amdgcn_mfma_f32_32x32x16_bf16(pk.s, us2bf(hg3), acc3, 0, 0, 0);
            accs = __builtin_amdgcn_mfma_f32_32x32x16_bf16(pk.s, ones, accs, 0, 0, 0);
        }
    }
    // publish per-wave row sums
    if (row == 0) {   // lanes 0 and 32
#pragma unroll
        for (int reg = 0; reg < 16; ++reg) {
            int r = (reg & 3) + 8 * (reg >> 2) + 4 * kh;
            sred[w][r] = accs[reg];
        }
    }
    __syncthreads();
    if (t < 32) psum[(size_t)nb * 32 + t] =
        (sred[0][t] + sred[1][t]) + (sred[2][t] + sred[3][t]);
    // sequential reduce of acc partials into w0 (red overlays dead ej planes)
#pragma unroll
    for (int src = 1; src < 4; ++src) {
        if (w == src) {
#pragma unroll
            for (int cg = 0; cg < 4; ++cg) {
                const f16v& av = (cg == 0) ? acc0 : (cg == 1) ? acc1 : (cg == 2) ? acc2 : acc3;
#pragma unroll
                for (int reg = 0; reg < 16; ++reg) {
                    int r = (reg & 3) + 8 * (reg >> 2) + 4 * kh;
                    red[r * 128 + cg * 32 + row] = av[reg];
                }
            }
        }
        __syncthreads();
        if (w == 0) {
#pragma unroll
            for (int cg = 0; cg < 4; ++cg) {
                f16v& av = (cg == 0) ? acc0 : (cg == 1) ? acc1 : (cg == 2) ? acc2 : acc3;
#pragma unroll
                for (int reg = 0; reg < 16; ++reg) {
                    int r = (reg & 3) + 8 * (reg >> 2) + 4 * kh;
                    av[reg] += red[r * 128 + cg * 32 + row];
                }
            }
        }
        __syncthreads();
    }
    if (w == 0) {
        float* pa = &pacc[(size_t)nb * 4096];
#pragma unroll
        for (int cg = 0; cg < 4; ++cg) {
            const f16v& av = (cg == 0) ? acc0 : (cg == 1) ? acc1 : (cg == 2) ? acc2 : acc3;
#pragma unroll
            for (int reg = 0; reg < 16; ++reg) {
                int r = (reg & 3) + 8 * (reg >> 2) + 4 * kh;
                pa[r * 128 + cg * 32 + row] = av[reg];
            }
        }
    }
    // ---- fused split-K finish: second block of the pair combines ----
    __threadfence();
    __syncthreads();
    if (t == 0) oldt_s = atomicAdd(&ticket[nb >> 1], 1u);
    __syncthreads();
    if (oldt_s == 1u) {
        __threadfence();
        const int p0 = nb & ~1, p1 = nb | 1;           // fixed order: half0 + half1
        const int rr = t >> 3, cb = (t & 7) * 16;
        float s = psum[(size_t)p0 * 32 + rr] + psum[(size_t)p1 * 32 + rr];
        float rinv = 1.0f / s;
        const float* a0p = &pacc[(size_t)p0 * 4096 + rr * 128 + cb];
        const float* a1p = &pacc[(size_t)p1 * 4096 + rr * 128 + cb];
        float* o = &out[(size_t)(n0 + rr) * KFc + k * FOUTc + cb];
#pragma unroll
        for (int c4 = 0; c4 < 4; ++c4) {
            f4 v0 = *(const f4*)(a0p + c4 * 4);
            f4 v1 = *(const f4*)(a1p + c4 * 4);
            f4 v;
#pragma unroll
            for (int j = 0; j < 4; ++j) v[j] = (v0[j] + v1[j]) * rinv;
            *(f4*)(o + c4 * 4) = v;
        }
    }
}

extern "C" void kernel_launch(void* const* d_in, const int* in_sizes, int n_in,
                              void* d_out, int out_size, void* d_ws, size_t ws_size,
                              hipStream_t stream) {
    const float* x   = (const float*)d_in[0];
    const int*   adj = (const int*)d_in[1];
    const float* W   = (const float*)d_in[2];
    const float* a   = (const float*)d_in[3];
    float* out = (float*)d_out;
    char* ws = (char*)d_ws;

    // layout (~23.4 MB): pacc aliases xb (dead after gemmh_bits)
    unsigned short* hB   = (unsigned short*)ws;                  // 0..4 MB
    unsigned short* xb   = (unsigned short*)(ws + (4u << 20));   // 4..8 MB (dead after gemmh)
    float*          pacc = (float*)(ws + (4u << 20));            // 4..20 MB
    unsigned short* WbT  = (unsigned short*)(ws + (20u << 20));  // 20..20.5 MB
    unsigned*       bits = (unsigned*)(ws + (21u << 20));        // 21..23 MB
    float*          ei   = (float*)(ws + (23u << 20));           // 64 KB
    float*          ejP  = ei + (size_t)NN * KHc;                // 64 KB
    float*          ejN  = ejP + (size_t)NN * KHc;               // 64 KB
    float*          psum = ejN + (size_t)NN * KHc;               // 128 KB
    unsigned*       ticket = (unsigned*)(psum + (size_t)1024 * 32);  // 2 KB

    prep_kernel<<<1089, 256, 0, stream>>>(x, W, xb, WbT, ticket);
    gemmh_bits_kernel<<<1536, 256, 0, stream>>>(xb, WbT, adj, hB, bits);
    e2_kernel<<<256, 256, 0, stream>>>(hB, a, ei, ejP, ejN);
    out_mfma_kernel<<<1024, 256, 0, stream>>>(bits, ei, ejP, ejN, hB, pacc, psum, ticket, out);
}

// Round 12
// 78.535 us; speedup vs baseline: 3.0387x; 3.0387x over previous
//
#include <hip/hip_runtime.h>
#include <hip/hip_bf16.h>

typedef float f4 __attribute__((ext_vector_type(4)));
typedef int   i4 __attribute__((ext_vector_type(4)));
typedef unsigned short us8 __attribute__((ext_vector_type(8)));
typedef short bfrag __attribute__((ext_vector_type(8)));     // 8 bf16
typedef float f16v __attribute__((ext_vector_type(16)));

constexpr int NN   = 4096;
constexpr int FINc = 512;
constexpr int FOUTc= 128;
constexpr int KHc  = 4;
constexpr int KFc  = 512;
constexpr float ALPHA = 0.2f;
constexpr float LOG2E = 1.44269504088896340736f;

static __device__ __forceinline__ unsigned short f2bf(float f) {
    unsigned u = __float_as_uint(f);
    return (unsigned short)((u + 0x7fffu + ((u >> 16) & 1u)) >> 16);   // RNE
}
static __device__ __forceinline__ float bf2f(unsigned short u) {
    return __uint_as_float(((unsigned)u) << 16);
}
static __device__ __forceinline__ bfrag us2bf(us8 v) {
    union { us8 u; bfrag s; } cv; cv.u = v; return cv.s;
}

// hB fragment layout (bf16): per head k, per 64-m chunk mc:
//   byte = k*1048576 + mc*16384 + ks*4096 + lg*2048 + col*16 + j*2
// where m = ks*16 + lg*8 + j, col in [0,128)

// ---------------- kernel 0: prep: x->xb (bf16) | W -> WbT[k][o][f] ----------------
__global__ __launch_bounds__(256) void prep_kernel(const float* __restrict__ x,
                                                   const float* __restrict__ W,
                                                   unsigned short* __restrict__ xb,
                                                   unsigned short* __restrict__ WbT) {
    __shared__ float tile[32 * 132];
    const int b = blockIdx.x, t = threadIdx.x;
    if (b < 1024) {                       // x cast: 8 per thread
        size_t base = ((size_t)b * 256 + t) * 8;
        f4 v0 = *(const f4*)&x[base];
        f4 v1 = *(const f4*)&x[base + 4];
        us8 o;
#pragma unroll
        for (int j = 0; j < 4; ++j) { o[j] = f2bf(v0[j]); o[4 + j] = f2bf(v1[j]); }
        *(us8*)&xb[base] = o;
    } else {                              // W transpose: 64 blocks, 32f x 128o tiles
        const int wb = b - 1024;
        const int k = wb >> 4, f0 = (wb & 15) * 32;
#pragma unroll
        for (int p = 0; p < 4; ++p) {
            int fl = p * 8 + (t >> 5);
            int oc = (t & 31) * 4;
            *(f4*)&tile[fl * 132 + oc] =
                *(const f4*)&W[(size_t)k * 65536 + (size_t)(f0 + fl) * 128 + oc];
        }
        __syncthreads();
        const int o = t >> 1, fh = (t & 1) * 16;
        alignas(16) unsigned short buf[16];
#pragma unroll
        for (int j = 0; j < 16; ++j) buf[j] = f2bf(tile[(fh + j) * 132 + o]);
        unsigned short* dst = &WbT[((size_t)k * 128 + o) * FINc + f0 + fh];
        *(us8*)dst       = *(const us8*)&buf[0];
        *(us8*)(dst + 8) = *(const us8*)&buf[8];
    }
}

// ---------------- kernel 1: gemmh (blocks 0..511) | adj->bits (blocks 512..1535) ----------------
__global__ __launch_bounds__(256) void gemmh_bits_kernel(const unsigned short* __restrict__ xb,
                                                         const unsigned short* __restrict__ WbT,
                                                         const int* __restrict__ adj,
                                                         unsigned short* __restrict__ hB,
                                                         unsigned* __restrict__ bits) {
    __shared__ char Ax[64 * 128];
    __shared__ char Bx[64 * 128];
    const int b = blockIdx.x, t = threadIdx.x;
    if (b >= 512) {                       // ---- bits: 1024 blocks x 16384 ints ----
        size_t i0 = (size_t)(b - 512) * 16384 + (size_t)t * 64;
        const int* ap = adj + i0;
        unsigned long long bb = 0ull;
#pragma unroll
        for (int c = 0; c < 16; ++c) {
            i4 v = *(const i4*)(ap + c * 4);
            unsigned n = (v[0] != 0 ? 1u : 0u) | (v[1] != 0 ? 2u : 0u)
                       | (v[2] != 0 ? 4u : 0u) | (v[3] != 0 ? 8u : 0u);
            bb |= (unsigned long long)n << (c * 4);
        }
        *(unsigned long long*)&bits[i0 >> 5] = bb;
        return;
    }
    const int wid = t >> 6, lane = t & 63;
    const int c0 = (b & 7) * 64, n0 = (b >> 3) * 64;
    const int head = c0 >> 7, ob = c0 & 127;
    const int srow = t >> 2, sseg = t & 3;
    const unsigned short* asrc = &xb[(size_t)(n0 + srow) * FINc + sseg * 16];
    const unsigned short* bsrc = &WbT[((size_t)(head * 128 + ob + srow)) * FINc + sseg * 16];
    const int rowbase = (wid & 1) * 32, colbase = (wid >> 1) * 32;
    f16v acc = {};
    for (int fc = 0; fc < FINc; fc += 64) {
        us8 a0 = *(const us8*)(asrc + fc), a1 = *(const us8*)(asrc + fc + 8);
        us8 b0 = *(const us8*)(bsrc + fc), b1 = *(const us8*)(bsrc + fc + 8);
        __syncthreads();
        {
            int byt = (sseg * 32) ^ ((srow & 7) << 4);
            char* pa = Ax + srow * 128;
            *(us8*)(pa + byt) = a0;  *(us8*)(pa + (byt ^ 16)) = a1;
            char* pb = Bx + srow * 128;
            *(us8*)(pb + byt) = b0;  *(us8*)(pb + (byt ^ 16)) = b1;
        }
        __syncthreads();
#pragma unroll
        for (int ks = 0; ks < 4; ++ks) {
            int kb = ks * 32 + ((lane >> 5) << 4);
            int ar = rowbase + (lane & 31);
            bfrag af = *(const bfrag*)(Ax + ar * 128 + (kb ^ ((ar & 7) << 4)));
            int bc = colbase + (lane & 31);
            bfrag bf = *(const bfrag*)(Bx + bc * 128 + (kb ^ ((bc & 7) << 4)));
            acc = __builtin_amdgcn_mfma_f32_32x32x16_bf16(af, bf, acc, 0, 0, 0);
        }
    }
    __syncthreads();
#pragma unroll
    for (int reg = 0; reg < 16; ++reg) {
        int row = rowbase + (reg & 3) + 8 * (reg >> 2) + 4 * (lane >> 5);
        int col = colbase + (lane & 31);
        *(unsigned short*)(Ax + row * 128 + ((col * 2) ^ ((row & 7) << 4))) = f2bf(acc[reg]);
    }
    __syncthreads();
    {
        const int col_l = t & 63;
        unsigned short* dstbase = hB + (size_t)head * 524288 + (size_t)(n0 >> 6) * 8192
                                     + (size_t)(ob + col_l) * 8;
#pragma unroll
        for (int g = 0; g < 2; ++g) {
            int o8 = (t >> 6) + g * 4;
            int ks = o8 >> 1, lg = o8 & 1;
            alignas(16) unsigned short buf[8];
#pragma unroll
            for (int j = 0; j < 8; ++j) {
                int r = o8 * 8 + j;
                buf[j] = *(const unsigned short*)(Ax + r * 128 + ((col_l * 2) ^ ((r & 7) << 4)));
            }
            *(us8*)(dstbase + ks * 2048 + lg * 1024) = *(const us8*)buf;
        }
    }
}

// ---------------- kernel 2: ei[n,k], ejT[k,n] from hB (pre-scaled by log2e) ----------------
__global__ __launch_bounds__(256) void e2_kernel(const unsigned short* __restrict__ hB,
                                                 const float* __restrict__ a,
                                                 float* __restrict__ ei,
                                                 float* __restrict__ ejT) {
    __shared__ unsigned short hs[8192];
    __shared__ float as[128], ad[128];
    __shared__ float pim[4][64], pjm[4][64];
    const int t = threadIdx.x;
    const int k = blockIdx.x >> 6;
    const int mc = blockIdx.x & 63;
    if (t < 128) as[t] = a[k * 256 + t] * LOG2E;
    else         ad[t - 128] = a[k * 256 + t] * LOG2E;
    const unsigned short* src = hB + ((size_t)k * 64 + mc) * 8192;
#pragma unroll
    for (int i = 0; i < 4; ++i) {
        int off = i * 2048 + t * 8;
        *(us8*)&hs[off] = *(const us8*)&src[off];
    }
    __syncthreads();
    const int m = t & 63, wq = t >> 6;
    const int base = (m >> 4) * 2048 + ((m >> 3) & 1) * 1024 + (m & 7);
    float si = 0.f, sj = 0.f;
#pragma unroll
    for (int cc = 0; cc < 32; ++cc) {
        int c = wq * 32 + cc;
        float v = bf2f(hs[base + c * 8]);
        si += v * as[c];
        sj += v * ad[c];
    }
    pim[wq][m] = si; pjm[wq][m] = sj;
    __syncthreads();
    if (t < 64) {
        ei[(mc * 64 + t) * KHc + k]        = pim[0][t] + pim[1][t] + pim[2][t] + pim[3][t];
        ejT[(size_t)k * NN + mc * 64 + t]  = pjm[0][t] + pjm[1][t] + pjm[2][t] + pjm[3][t];
    }
}

// ---------------- kernel 3: out = softmax(P) @ H, full m per block ----------------
// 512 blocks: block = (k, 32-row tile), full 4096 m. 4 waves each own a private
// 1024-m quarter (register-P, zero in-loop barriers; loop body identical to R10).
// Epilogue: sequential LDS reduce of wave partials, scale by in-block 1/denominator,
// write out directly. No pacc/psum/combine.
__global__ __launch_bounds__(256, 2) void out_mfma_kernel(const unsigned* __restrict__ bits,
                                                          const float* __restrict__ ei,
                                                          const float* __restrict__ ejT,
                                                          const unsigned short* __restrict__ hB,
                                                          float* __restrict__ out) {
    __shared__ unsigned bitsL[4][1056];     // 32 rows x 33 words per wave (padded)
    __shared__ float ejred[4096];           // ejL [4][1024] during loop; red after
    __shared__ float sred[4][32];
    __shared__ float lsum[32];
    const int bid = blockIdx.x;
    const int nb  = (bid & 7) * 64 + (bid >> 3);    // bijective: 512 = 8*64
    const int k   = nb >> 7;
    const int n0  = (nb & 127) * 32;
    const int t = threadIdx.x, lane = t & 63, w = t >> 6;
    const int row = lane & 31, kh = lane >> 5;
    const int mq  = w * 1024;                       // wave's private m range
    {   // stage bits (wave-private): each lane copies one half-row (16 words)
        int r = lane >> 1, cb = (lane & 1) * 16;
        const unsigned* src = &bits[(size_t)(n0 + r) * 128 + (mq >> 5) + cb];
        unsigned* dst = &bitsL[w][r * 33 + cb];
#pragma unroll
        for (int c = 0; c < 16; ++c) dst[c] = src[c];
    }
    {   // stage ej (wave-private): 16 floats per lane
        const float* src = &ejT[(size_t)k * NN + mq + lane * 16];
        float* dst = &ejred[w * 1024 + lane * 16];
#pragma unroll
        for (int c = 0; c < 4; ++c) *(f4*)(dst + c * 4) = *(const f4*)(src + c * 4);
    }
    const float eiv = ei[(n0 + row) * KHc + k];
    const char* hbase = (const char*)hB + (size_t)k * 1048576 + (size_t)(mq >> 6) * 16384
                        + kh * 2048 + row * 16;
    bfrag ones;
#pragma unroll
    for (int j = 0; j < 8; ++j) ones[j] = (short)0x3F80;   // bf16 1.0
    f16v acc0 = {}, acc1 = {}, acc2 = {}, acc3 = {}, accs = {};

    for (int it = 0; it < 16; ++it) {
        const char* hc = hbase + (size_t)it * 16384;
        unsigned bwA = bitsL[w][row * 33 + it * 2];
        unsigned bwB = bitsL[w][row * 33 + it * 2 + 1];
#pragma unroll
        for (int ks = 0; ks < 4; ++ks) {
            us8 hg0 = *(const us8*)(hc + ks * 4096);
            us8 hg1 = *(const us8*)(hc + ks * 4096 + 512);
            us8 hg2 = *(const us8*)(hc + ks * 4096 + 1024);
            us8 hg3 = *(const us8*)(hc + ks * 4096 + 1536);
            const int eb = w * 1024 + it * 64 + ks * 16 + kh * 8;
            f4 ej0 = *(const f4*)&ejred[eb];
            f4 ej1 = *(const f4*)&ejred[eb + 4];
            unsigned bw = ((ks & 2) ? bwB : bwA) >> ((ks & 1) * 16 + kh * 8);
            float p[8];
#pragma unroll
            for (int j = 0; j < 8; ++j) {
                float sc = eiv + (j < 4 ? ej0[j] : ej1[j - 4]);
                sc = fmaxf(sc, ALPHA * sc);
                float pp = exp2f(sc);
                p[j] = ((bw >> j) & 1) ? pp : 0.f;
            }
            union { unsigned u[4]; bfrag s; } pk;
#pragma unroll
            for (int j = 0; j < 4; ++j) {
                float2 fp; fp.x = p[2 * j]; fp.y = p[2 * j + 1];
                __hip_bfloat162 b2 = __float22bfloat162_rn(fp);
                pk.u[j] = *reinterpret_cast<unsigned*>(&b2);
            }
            acc0 = __builtin_amdgcn_mfma_f32_32x32x16_bf16(pk.s, us2bf(hg0), acc0, 0, 0, 0);
            acc1 = __builtin_amdgcn_mfma_f32_32x32x16_bf16(pk.s, us2bf(hg1), acc1, 0, 0, 0);
            acc2 = __builtin_amdgcn_mfma_f32_32x32x16_bf16(pk.s, us2bf(hg2), acc2, 0, 0, 0);
            acc3 = __builtin_amdgcn_mfma_f32_32x32x16_bf16(pk.s, us2bf(hg3), acc3, 0, 0, 0);
            accs = __builtin_amdgcn_mfma_f32_32x32x16_bf16(pk.s, ones, accs, 0, 0, 0);
        }
    }
    // publish per-wave row sums
    if (row == 0) {   // lanes 0 and 32
#pragma unroll
        for (int reg = 0; reg < 16; ++reg) {
            int r = (reg & 3) + 8 * (reg >> 2) + 4 * kh;
            sred[w][r] = accs[reg];
        }
    }
    __syncthreads();
    if (t < 32) lsum[t] = 1.0f / ((sred[0][t] + sred[1][t]) + (sred[2][t] + sred[3][t]));
    // sequential reduce of acc partials into w0 (red overlays dead ejL plane)
    float* red = ejred;
#pragma unroll
    for (int src = 1; src < 4; ++src) {
        if (w == src) {
#pragma unroll
            for (int cg = 0; cg < 4; ++cg) {
                const f16v& av = (cg == 0) ? acc0 : (cg == 1) ? acc1 : (cg == 2) ? acc2 : acc3;
#pragma unroll
                for (int reg = 0; reg < 16; ++reg) {
                    int r = (reg & 3) + 8 * (reg >> 2) + 4 * kh;
                    red[r * 128 + cg * 32 + row] = av[reg];
                }
            }
        }
        __syncthreads();
        if (w == 0) {
#pragma unroll
            for (int cg = 0; cg < 4; ++cg) {
                f16v& av = (cg == 0) ? acc0 : (cg == 1) ? acc1 : (cg == 2) ? acc2 : acc3;
#pragma unroll
                for (int reg = 0; reg < 16; ++reg) {
                    int r = (reg & 3) + 8 * (reg >> 2) + 4 * kh;
                    av[reg] += red[r * 128 + cg * 32 + row];
                }
            }
        }
        __syncthreads();
    }
    if (w == 0) {
#pragma unroll
        for (int cg = 0; cg < 4; ++cg) {
            const f16v& av = (cg == 0) ? acc0 : (cg == 1) ? acc1 : (cg == 2) ? acc2 : acc3;
#pragma unroll
            for (int reg = 0; reg < 16; ++reg) {
                int r = (reg & 3) + 8 * (reg >> 2) + 4 * kh;
                out[(size_t)(n0 + r) * KFc + k * FOUTc + cg * 32 + row] = av[reg] * lsum[r];
            }
        }
    }
}

extern "C" void kernel_launch(void* const* d_in, const int* in_sizes, int n_in,
                              void* d_out, int out_size, void* d_ws, size_t ws_size,
                              hipStream_t stream) {
    const float* x   = (const float*)d_in[0];
    const int*   adj = (const int*)d_in[1];
    const float* W   = (const float*)d_in[2];
    const float* a   = (const float*)d_in[3];
    float* out = (float*)d_out;
    char* ws = (char*)d_ws;

    unsigned short* hB   = (unsigned short*)ws;                  // 0..4 MB
    unsigned short* xb   = (unsigned short*)(ws + (4u << 20));   // 4..8 MB
    unsigned short* WbT  = (unsigned short*)(ws + (20u << 20));  // 20..20.5 MB
    unsigned*       bits = (unsigned*)(ws + (21u << 20));        // 21..23 MB
    float*          ei   = (float*)(ws + (23u << 20));           // 64 KB
    float*          ejT  = ei + (size_t)NN * KHc;                // 64 KB

    prep_kernel<<<1088, 256, 0, stream>>>(x, W, xb, WbT);
    gemmh_bits_kernel<<<1536, 256, 0, stream>>>(xb, WbT, adj, hB, bits);
    e2_kernel<<<256, 256, 0, stream>>>(hB, a, ei, ejT);
    out_mfma_kernel<<<512, 256, 0, stream>>>(bits, ei, ejT, hB, out);
}

// Round 13
// 74.048 us; speedup vs baseline: 3.2228x; 1.0606x over previous
//
#include <hip/hip_runtime.h>
#include <hip/hip_bf16.h>

typedef float f4 __attribute__((ext_vector_type(4)));
typedef int   i4 __attribute__((ext_vector_type(4)));
typedef unsigned short us8 __attribute__((ext_vector_type(8)));
typedef short bfrag __attribute__((ext_vector_type(8)));     // 8 bf16
typedef float f16v __attribute__((ext_vector_type(16)));

constexpr int NN   = 4096;
constexpr int FINc = 512;
constexpr int FOUTc= 128;
constexpr int KHc  = 4;
constexpr int KFc  = 512;
constexpr float LOG2E = 1.44269504088896340736f;

static __device__ __forceinline__ unsigned short f2bf(float f) {
    unsigned u = __float_as_uint(f);
    return (unsigned short)((u + 0x7fffu + ((u >> 16) & 1u)) >> 16);   // RNE
}
static __device__ __forceinline__ float bf2f(unsigned short u) {
    return __uint_as_float(((unsigned)u) << 16);
}
static __device__ __forceinline__ bfrag us2bf(us8 v) {
    union { us8 u; bfrag s; } cv; cv.u = v; return cv.s;
}

// hB fragment layout (bf16): per head k, per 64-m chunk mc:
//   byte = k*1048576 + mc*16384 + ks*4096 + lg*2048 + col*16 + j*2
// where m = ks*16 + lg*8 + j, col in [0,128)

// ---------------- kernel 0: prep: x->xb (bf16) | W -> WbT[k][o][f] ----------------
__global__ __launch_bounds__(256) void prep_kernel(const float* __restrict__ x,
                                                   const float* __restrict__ W,
                                                   unsigned short* __restrict__ xb,
                                                   unsigned short* __restrict__ WbT) {
    __shared__ float tile[32 * 132];
    const int b = blockIdx.x, t = threadIdx.x;
    if (b < 1024) {                       // x cast: 8 per thread
        size_t base = ((size_t)b * 256 + t) * 8;
        f4 v0 = *(const f4*)&x[base];
        f4 v1 = *(const f4*)&x[base + 4];
        us8 o;
#pragma unroll
        for (int j = 0; j < 4; ++j) { o[j] = f2bf(v0[j]); o[4 + j] = f2bf(v1[j]); }
        *(us8*)&xb[base] = o;
    } else {                              // W transpose: 64 blocks, 32f x 128o tiles
        const int wb = b - 1024;
        const int k = wb >> 4, f0 = (wb & 15) * 32;
#pragma unroll
        for (int p = 0; p < 4; ++p) {
            int fl = p * 8 + (t >> 5);
            int oc = (t & 31) * 4;
            *(f4*)&tile[fl * 132 + oc] =
                *(const f4*)&W[(size_t)k * 65536 + (size_t)(f0 + fl) * 128 + oc];
        }
        __syncthreads();
        const int o = t >> 1, fh = (t & 1) * 16;
        alignas(16) unsigned short buf[16];
#pragma unroll
        for (int j = 0; j < 16; ++j) buf[j] = f2bf(tile[(fh + j) * 132 + o]);
        unsigned short* dst = &WbT[((size_t)k * 128 + o) * FINc + f0 + fh];
        *(us8*)dst       = *(const us8*)&buf[0];
        *(us8*)(dst + 8) = *(const us8*)&buf[8];
    }
}

// ---------------- kernel 1: gemmh (blocks 0..511) | adj->bits (blocks 512..1535) ----------------
__global__ __launch_bounds__(256) void gemmh_bits_kernel(const unsigned short* __restrict__ xb,
                                                         const unsigned short* __restrict__ WbT,
                                                         const int* __restrict__ adj,
                                                         unsigned short* __restrict__ hB,
                                                         unsigned* __restrict__ bits) {
    __shared__ char Ax[64 * 128];
    __shared__ char Bx[64 * 128];
    const int b = blockIdx.x, t = threadIdx.x;
    if (b >= 512) {                       // ---- bits: 1024 blocks x 16384 ints ----
        size_t i0 = (size_t)(b - 512) * 16384 + (size_t)t * 64;
        const int* ap = adj + i0;
        unsigned long long bb = 0ull;
#pragma unroll
        for (int c = 0; c < 16; ++c) {
            i4 v = *(const i4*)(ap + c * 4);
            unsigned n = (v[0] != 0 ? 1u : 0u) | (v[1] != 0 ? 2u : 0u)
                       | (v[2] != 0 ? 4u : 0u) | (v[3] != 0 ? 8u : 0u);
            bb |= (unsigned long long)n << (c * 4);
        }
        *(unsigned long long*)&bits[i0 >> 5] = bb;
        return;
    }
    const int wid = t >> 6, lane = t & 63;
    const int c0 = (b & 7) * 64, n0 = (b >> 3) * 64;
    const int head = c0 >> 7, ob = c0 & 127;
    const int srow = t >> 2, sseg = t & 3;
    const unsigned short* asrc = &xb[(size_t)(n0 + srow) * FINc + sseg * 16];
    const unsigned short* bsrc = &WbT[((size_t)(head * 128 + ob + srow)) * FINc + sseg * 16];
    const int rowbase = (wid & 1) * 32, colbase = (wid >> 1) * 32;
    f16v acc = {};
    for (int fc = 0; fc < FINc; fc += 64) {
        us8 a0 = *(const us8*)(asrc + fc), a1 = *(const us8*)(asrc + fc + 8);
        us8 b0 = *(const us8*)(bsrc + fc), b1 = *(const us8*)(bsrc + fc + 8);
        __syncthreads();
        {
            int byt = (sseg * 32) ^ ((srow & 7) << 4);
            char* pa = Ax + srow * 128;
            *(us8*)(pa + byt) = a0;  *(us8*)(pa + (byt ^ 16)) = a1;
            char* pb = Bx + srow * 128;
            *(us8*)(pb + byt) = b0;  *(us8*)(pb + (byt ^ 16)) = b1;
        }
        __syncthreads();
#pragma unroll
        for (int ks = 0; ks < 4; ++ks) {
            int kb = ks * 32 + ((lane >> 5) << 4);
            int ar = rowbase + (lane & 31);
            bfrag af = *(const bfrag*)(Ax + ar * 128 + (kb ^ ((ar & 7) << 4)));
            int bc = colbase + (lane & 31);
            bfrag bf = *(const bfrag*)(Bx + bc * 128 + (kb ^ ((bc & 7) << 4)));
            acc = __builtin_amdgcn_mfma_f32_32x32x16_bf16(af, bf, acc, 0, 0, 0);
        }
    }
    __syncthreads();
#pragma unroll
    for (int reg = 0; reg < 16; ++reg) {
        int row = rowbase + (reg & 3) + 8 * (reg >> 2) + 4 * (lane >> 5);
        int col = colbase + (lane & 31);
        *(unsigned short*)(Ax + row * 128 + ((col * 2) ^ ((row & 7) << 4))) = f2bf(acc[reg]);
    }
    __syncthreads();
    {
        const int col_l = t & 63;
        unsigned short* dstbase = hB + (size_t)head * 524288 + (size_t)(n0 >> 6) * 8192
                                     + (size_t)(ob + col_l) * 8;
#pragma unroll
        for (int g = 0; g < 2; ++g) {
            int o8 = (t >> 6) + g * 4;
            int ks = o8 >> 1, lg = o8 & 1;
            alignas(16) unsigned short buf[8];
#pragma unroll
            for (int j = 0; j < 8; ++j) {
                int r = o8 * 8 + j;
                buf[j] = *(const unsigned short*)(Ax + r * 128 + ((col_l * 2) ^ ((r & 7) << 4)));
            }
            *(us8*)(dstbase + ks * 2048 + lg * 1024) = *(const us8*)buf;
        }
    }
}

// ---------------- kernel 2: ei[n,k], ejT[k,n] from hB (pre-scaled by log2e) ----------------
__global__ __launch_bounds__(256) void e2_kernel(const unsigned short* __restrict__ hB,
                                                 const float* __restrict__ a,
                                                 float* __restrict__ ei,
                                                 float* __restrict__ ejT) {
    __shared__ unsigned short hs[8192];
    __shared__ float as[128], ad[128];
    __shared__ float pim[4][64], pjm[4][64];
    const int t = threadIdx.x;
    const int k = blockIdx.x >> 6;
    const int mc = blockIdx.x & 63;
    if (t < 128) as[t] = a[k * 256 + t] * LOG2E;
    else         ad[t - 128] = a[k * 256 + t] * LOG2E;
    const unsigned short* src = hB + ((size_t)k * 64 + mc) * 8192;
#pragma unroll
    for (int i = 0; i < 4; ++i) {
        int off = i * 2048 + t * 8;
        *(us8*)&hs[off] = *(const us8*)&src[off];
    }
    __syncthreads();
    const int m = t & 63, wq = t >> 6;
    const int base = (m >> 4) * 2048 + ((m >> 3) & 1) * 1024 + (m & 7);
    float si = 0.f, sj = 0.f;
#pragma unroll
    for (int cc = 0; cc < 32; ++cc) {
        int c = wq * 32 + cc;
        float v = bf2f(hs[base + c * 8]);
        si += v * as[c];
        sj += v * ad[c];
    }
    pim[wq][m] = si; pjm[wq][m] = sj;
    __syncthreads();
    if (t < 64) {
        ei[(mc * 64 + t) * KHc + k]        = pim[0][t] + pim[1][t] + pim[2][t] + pim[3][t];
        ejT[(size_t)k * NN + mc * 64 + t]  = pjm[0][t] + pjm[1][t] + pjm[2][t] + pjm[3][t];
    }
}

// ---------------- kernel 3: out = softmax(P) @ H, full m, 8 waves ----------------
// 512 blocks x 512 threads: block = (k, 32-row tile); 8 waves each own a private
// 512-m slice with register-P (zero in-loop barriers). Factorized P-gen:
// P'[n,m] = mask ? max(EjP[m], C_n*EjN[m]) : 0, row factor exp2(ei) cancels in
// softmax; EjP/EjN computed once per column at staging. Sequential LDS reduce,
// in-block denominator, direct out write.
__global__ __launch_bounds__(512, 4) void out_mfma_kernel(const unsigned* __restrict__ bits,
                                                          const float* __restrict__ ei,
                                                          const float* __restrict__ ejT,
                                                          const unsigned short* __restrict__ hB,
                                                          float* __restrict__ out) {
    __shared__ unsigned bitsL[8][544];      // 32 rows x 17 (16 words + pad) per wave
    __shared__ float ejPL[4096];            // [8][512]; reused as red after loop
    __shared__ float ejNL[4096];            // [8][512]
    __shared__ float sred[8][32];
    __shared__ float lsum[32];
    const int bid = blockIdx.x;
    const int nb  = (bid & 7) * 64 + (bid >> 3);    // bijective: 512 = 8*64
    const int k   = nb >> 7;
    const int n0  = (nb & 127) * 32;
    const int t = threadIdx.x, lane = t & 63, w = t >> 6;
    const int row = lane & 31, kh = lane >> 5;
    const int mq  = w * 512;                        // wave's private m range
    {   // stage bits (wave-private): lane pair covers one row (16 words)
        int r = lane >> 1, cb = (lane & 1) * 8;
        const unsigned* src = &bits[(size_t)(n0 + r) * 128 + (mq >> 5) + cb];
        unsigned* dst = &bitsL[w][r * 17 + cb];
#pragma unroll
        for (int c = 0; c < 8; ++c) dst[c] = src[c];
    }
    {   // stage EjP/EjN (wave-private): 8 columns per lane, exp2 once per column
        const float* src = &ejT[(size_t)k * NN + mq + lane * 8];
        f4 v0 = *(const f4*)src;
        f4 v1 = *(const f4*)(src + 4);
        float* dP = &ejPL[w * 512 + lane * 8];
        float* dN = &ejNL[w * 512 + lane * 8];
#pragma unroll
        for (int c = 0; c < 4; ++c) {
            dP[c]     = exp2f(v0[c]);
            dP[c + 4] = exp2f(v1[c]);
            dN[c]     = exp2f(0.2f * v0[c]);
            dN[c + 4] = exp2f(0.2f * v1[c]);
        }
    }
    const float eiv = ei[(n0 + row) * KHc + k];
    const float C = exp2f(-0.8f * eiv);
    const char* hbase = (const char*)hB + (size_t)k * 1048576 + (size_t)(mq >> 6) * 16384
                        + kh * 2048 + row * 16;
    bfrag ones;
#pragma unroll
    for (int j = 0; j < 8; ++j) ones[j] = (short)0x3F80;   // bf16 1.0
    f16v acc0 = {}, acc1 = {}, acc2 = {}, acc3 = {}, accs = {};

    for (int it = 0; it < 8; ++it) {
        const char* hc = hbase + (size_t)it * 16384;
        unsigned bwA = bitsL[w][row * 17 + it * 2];
        unsigned bwB = bitsL[w][row * 17 + it * 2 + 1];
#pragma unroll
        for (int ks = 0; ks < 4; ++ks) {
            us8 hg0 = *(const us8*)(hc + ks * 4096);
            us8 hg1 = *(const us8*)(hc + ks * 4096 + 512);
            us8 hg2 = *(const us8*)(hc + ks * 4096 + 1024);
            us8 hg3 = *(const us8*)(hc + ks * 4096 + 1536);
            const int eb = w * 512 + it * 64 + ks * 16 + kh * 8;
            f4 jp0 = *(const f4*)&ejPL[eb];
            f4 jp1 = *(const f4*)&ejPL[eb + 4];
            f4 jn0 = *(const f4*)&ejNL[eb];
            f4 jn1 = *(const f4*)&ejNL[eb + 4];
            unsigned bw = ((ks & 2) ? bwB : bwA) >> ((ks & 1) * 16 + kh * 8);
            float p[8];
#pragma unroll
            for (int j = 0; j < 8; ++j) {
                float jp = (j < 4) ? jp0[j] : jp1[j - 4];
                float jn = (j < 4) ? jn0[j] : jn1[j - 4];
                float v = fmaxf(jp, C * jn);           // exp2(lrelu(s))/exp2(ei)
                p[j] = ((bw >> j) & 1) ? v : 0.f;
            }
            union { unsigned u[4]; bfrag s; } pk;
#pragma unroll
            for (int j = 0; j < 4; ++j) {
                float2 fp; fp.x = p[2 * j]; fp.y = p[2 * j + 1];
                __hip_bfloat162 b2 = __float22bfloat162_rn(fp);
                pk.u[j] = *reinterpret_cast<unsigned*>(&b2);
            }
            acc0 = __builtin_amdgcn_mfma_f32_32x32x16_bf16(pk.s, us2bf(hg0), acc0, 0, 0, 0);
            acc1 = __builtin_amdgcn_mfma_f32_32x32x16_bf16(pk.s, us2bf(hg1), acc1, 0, 0, 0);
            acc2 = __builtin_amdgcn_mfma_f32_32x32x16_bf16(pk.s, us2bf(hg2), acc2, 0, 0, 0);
            acc3 = __builtin_amdgcn_mfma_f32_32x32x16_bf16(pk.s, us2bf(hg3), acc3, 0, 0, 0);
            accs = __builtin_amdgcn_mfma_f32_32x32x16_bf16(pk.s, ones, accs, 0, 0, 0);
        }
    }
    // publish per-wave row sums
    if (row == 0) {   // lanes 0 and 32 of each wave
#pragma unroll
        for (int reg = 0; reg < 16; ++reg) {
            int r = (reg & 3) + 8 * (reg >> 2) + 4 * kh;
            sred[w][r] = accs[reg];
        }
    }
    __syncthreads();
    if (t < 32) {
        float s = ((sred[0][t] + sred[1][t]) + (sred[2][t] + sred[3][t]))
                + ((sred[4][t] + sred[5][t]) + (sred[6][t] + sred[7][t]));
        lsum[t] = 1.0f / s;
    }
    // sequential reduce of acc partials into w0 (red overlays dead ejPL plane)
    float* red = ejPL;
#pragma unroll
    for (int src = 1; src < 8; ++src) {
        if (w == src) {
#pragma unroll
            for (int cg = 0; cg < 4; ++cg) {
                const f16v& av = (cg == 0) ? acc0 : (cg == 1) ? acc1 : (cg == 2) ? acc2 : acc3;
#pragma unroll
                for (int reg = 0; reg < 16; ++reg) {
                    int r = (reg & 3) + 8 * (reg >> 2) + 4 * kh;
                    red[r * 128 + cg * 32 + row] = av[reg];
                }
            }
        }
        __syncthreads();
        if (w == 0) {
#pragma unroll
            for (int cg = 0; cg < 4; ++cg) {
                f16v& av = (cg == 0) ? acc0 : (cg == 1) ? acc1 : (cg == 2) ? acc2 : acc3;
#pragma unroll
                for (int reg = 0; reg < 16; ++reg) {
                    int r = (reg & 3) + 8 * (reg >> 2) + 4 * kh;
                    av[reg] += red[r * 128 + cg * 32 + row];
                }
            }
        }
        __syncthreads();
    }
    if (w == 0) {
#pragma unroll
        for (int cg = 0; cg < 4; ++cg) {
            const f16v& av = (cg == 0) ? acc0 : (cg == 1) ? acc1 : (cg == 2) ? acc2 : acc3;
#pragma unroll
            for (int reg = 0; reg < 16; ++reg) {
                int r = (reg & 3) + 8 * (reg >> 2) + 4 * kh;
                out[(size_t)(n0 + r) * KFc + k * FOUTc + cg * 32 + row] = av[reg] * lsum[r];
            }
        }
    }
}

extern "C" void kernel_launch(void* const* d_in, const int* in_sizes, int n_in,
                              void* d_out, int out_size, void* d_ws, size_t ws_size,
                              hipStream_t stream) {
    const float* x   = (const float*)d_in[0];
    const int*   adj = (const int*)d_in[1];
    const float* W   = (const float*)d_in[2];
    const float* a   = (const float*)d_in[3];
    float* out = (float*)d_out;
    char* ws = (char*)d_ws;

    unsigned short* hB   = (unsigned short*)ws;                  // 0..4 MB
    unsigned short* xb   = (unsigned short*)(ws + (4u << 20));   // 4..8 MB
    unsigned short* WbT  = (unsigned short*)(ws + (20u << 20));  // 20..20.5 MB
    unsigned*       bits = (unsigned*)(ws + (21u << 20));        // 21..23 MB
    float*          ei   = (float*)(ws + (23u << 20));           // 64 KB
    float*          ejT  = ei + (size_t)NN * KHc;                // 64 KB

    prep_kernel<<<1088, 256, 0, stream>>>(x, W, xb, WbT);
    gemmh_bits_kernel<<<1536, 256, 0, stream>>>(xb, WbT, adj, hB, bits);
    e2_kernel<<<256, 256, 0, stream>>>(hB, a, ei, ejT);
    out_mfma_kernel<<<512, 512, 0, stream>>>(bits, ei, ejT, hB, out);
}